// Round 7
// baseline (368.275 us; speedup 1.0000x reference)
//
#include <hip/hip_runtime.h>
#include <math.h>

#define NN     16384
#define EE     600000
#define HIDN   128
#define NFT    32
#define NGAUSS 50
#define NLAY   6
#define TABN   8192
#define CUTF   10.0f

typedef float f32x4  __attribute__((ext_vector_type(4)));
typedef short bf16x8 __attribute__((ext_vector_type(8)));

__device__ __forceinline__ float ssp(float x) {
    // softplus(x) - log(2), numerically stable
    return fmaxf(x, 0.0f) + log1pf(__expf(-fabsf(x))) - 0.69314718055994531f;
}

__device__ __forceinline__ short f2bf(float x) {
    // f32 -> bf16 round-to-nearest-even
    union { float f; unsigned u; } v; v.f = x;
    unsigned r = v.u + 0x7fffu + ((v.u >> 16) & 1u);
    return (short)(r >> 16);
}

// ---------------------------------------------------------------- row_ptr ---
// Real edges (mask>0.5) are a prefix with dst ascending; padding after.
// key(e) = real ? dst[e] : INT_MAX is monotone -> per-thread lower_bound.
__global__ void build_rowptr(const int* __restrict__ dst, const float* __restrict__ mask,
                             int* __restrict__ rp) {
    int n = blockIdx.x * blockDim.x + threadIdx.x;
    if (n > NN) return;
    int lo = 0, hi = EE;
    while (lo < hi) {
        int mid = (lo + hi) >> 1;
        int key = (mask[mid] > 0.5f) ? dst[mid] : 0x7fffffff;
        if (key < n) lo = mid + 1; else hi = mid;
    }
    rp[n] = lo;
}

// ------------------------------------------------------------- edge geom ----
// geo[e] = (d * TABSCALE, cutoff_coeff)
__global__ void edge_geom(const int* __restrict__ ei, const float* __restrict__ pos,
                          const float* __restrict__ mask, float2* __restrict__ geo) {
    int e = blockIdx.x * blockDim.x + threadIdx.x;
    if (e >= EE) return;
    int s = ei[e], t = ei[EE + e];
    float dx = pos[s * 3 + 0] - pos[t * 3 + 0];
    float dy = pos[s * 3 + 1] - pos[t * 3 + 1];
    float dz = pos[s * 3 + 2] - pos[t * 3 + 2];
    float d = sqrtf(dx * dx + dy * dy + dz * dz);
    float cc = 0.5f * (cosf(d * 0.31415926535897932f) + 1.0f) * mask[e];
    geo[e] = make_float2(d * ((TABN - 1) / CUTF), cc);
}

// ----------------------------------------------------------- table build ----
__global__ void tab_kernel(const float* __restrict__ w1, const float* __restrict__ b1,
                           const float* __restrict__ w2, const float* __restrict__ b2,
                           float* __restrict__ tab) {
    __shared__ float ea[8][NGAUSS];
    __shared__ float t1[8][NFT];
    int t = threadIdx.x, f = t & 31, g = t >> 5;
    int id = blockIdx.x * 8 + g;           // 0 .. NLAY*TABN-1 exact
    int l = id / TABN, ent = id % TABN;
    float d = ent * (CUTF / (TABN - 1));
    const float delta = CUTF / (NGAUSS - 1);
    const float coeff = -0.5f / (delta * delta);
    for (int gg = f; gg < NGAUSS; gg += 32) {
        float diff = d - gg * delta;
        ea[g][gg] = __expf(coeff * diff * diff);
    }
    __syncthreads();
    float a = b1[l * NFT + f];
    const float* w1l = w1 + l * NGAUSS * NFT;
    #pragma unroll
    for (int gg = 0; gg < NGAUSS; ++gg)
        a = fmaf(ea[g][gg], w1l[gg * NFT + f], a);
    t1[g][f] = ssp(a);
    __syncthreads();
    float c = b2[l * NFT + f];
    const float* w2l = w2 + l * NFT * NFT;
    #pragma unroll
    for (int k = 0; k < NFT; ++k)
        c = fmaf(t1[g][k], w2l[k * NFT + f], c);
    tab[(size_t)id * NFT + f] = c;
}

// -------------------------------------------------------- pack tab2 ---------
// tab2[l][ent][f] = (tab[l][ent][f], tab[l][ent+1][f]) -> one 8B lerp load
__global__ void pack_tab2(const float* __restrict__ tab, float2* __restrict__ tab2) {
    int id = blockIdx.x * blockDim.x + threadIdx.x;    // NLAY*TABN*NFT
    if (id >= NLAY * TABN * NFT) return;
    int ent = (id >> 5) % TABN;
    float x = tab[id];
    float y = (ent < TABN - 1) ? tab[id + NFT] : x;
    tab2[id] = make_float2(x, y);
}

// ---------------------------------------------------------------- init h ----
__global__ void init_h(const int* __restrict__ z, const float4* __restrict__ emb4,
                       float4* __restrict__ h4) {
    int tid = blockIdx.x * blockDim.x + threadIdx.x;   // N*32 threads
    int n = tid >> 5, c = tid & 31;
    h4[tid] = emb4[(size_t)z[n] * 32 + c];
}

// --------------------------------------------------------- weight prep ------
//  l2wT[l][f<128][k<32]  = l2w[l][k][f]
//  lwT [l][f<128][k<128] = lw [l][k][f]
//  l1T [l][f<32 ][k<128] = l1 [l][k][f]
__global__ void prep_weights(const float* __restrict__ l2w, const float* __restrict__ lww,
                             const float* __restrict__ l1w,
                             short* __restrict__ l2wT, short* __restrict__ lwT,
                             short* __restrict__ l1T) {
    const int per = 4096 + 16384 + 4096;   // 24576 per layer
    int id = blockIdx.x * blockDim.x + threadIdx.x;
    if (id >= NLAY * per) return;
    int l = id / per, r = id % per;
    if (r < 4096) {
        int f = r >> 5, k = r & 31;
        l2wT[l * 4096 + f * 32 + k] = f2bf(l2w[l * 4096 + k * 128 + f]);
    } else if (r < 4096 + 16384) {
        int q = r - 4096; int f = q >> 7, k = q & 127;
        lwT[l * 16384 + f * 128 + k] = f2bf(lww[l * 16384 + k * 128 + f]);
    } else {
        int q = r - 20480; int f = q >> 7, k = q & 127;   // f<32, k<128
        l1T[l * 4096 + f * 128 + k] = f2bf(l1w[l * 4096 + k * 32 + f]);
    }
}

// ------------------------------------------------- hw = h@l1 (layer 0) ------
__global__ void hw_kernel(const float* __restrict__ h, const float* __restrict__ l1,
                          float* __restrict__ hw) {
    __shared__ float l1s[HIDN * NFT];
    int t = threadIdx.x, f = t & 31, nl = t >> 5;
    for (int i = t; i < HIDN * NFT / 4; i += 256)
        ((float4*)l1s)[i] = ((const float4*)l1)[i];
    __syncthreads();
    int n = blockIdx.x * 8 + nl;
    const float4* h4 = (const float4*)(h + (size_t)n * HIDN);
    float acc = 0.0f;
    #pragma unroll
    for (int k4 = 0; k4 < 32; ++k4) {
        float4 hv = h4[k4];
        acc = fmaf(hv.x, l1s[(k4 * 4 + 0) * NFT + f], acc);
        acc = fmaf(hv.y, l1s[(k4 * 4 + 1) * NFT + f], acc);
        acc = fmaf(hv.z, l1s[(k4 * 4 + 2) * NFT + f], acc);
        acc = fmaf(hv.w, l1s[(k4 * 4 + 3) * NFT + f], acc);
    }
    hw[(size_t)n * NFT + f] = acc;
}

// ================== fused layer: edge aggregate + node update ==============
// Per block (16 nodes, 256 thr = 4 waves):
//   1) m[n] = sum_e hw[src]*W(d)*cc  -- wave w owns nodes nb+4w..+3, processed
//      as FOUR INTERLEAVED independent chains (ILP) so each wave sustains 4
//      concurrent L2 load chains (round-6's serial 4-node loop was the
//      regression: 4x less memory-level parallelism).
//   2) x = ssp(m@l2w+l2b); h += x@lw+lb; hw_next = h_new@l1[l+1]  (MFMA)
// hw ping-pongs across layers (phase-C write vs other blocks' phase-1 read).
// mfma_f32_16x16x32_bf16 layouts (m89/m91-verified):
//   A: lane(16g+r) holds A[r][8g..8g+7];  B: lane(16g+c) holds B[8g..8g+7][c]
//   C/D: col = lane&15, row = 4*(lane>>4) + reg
// xs/hs XOR-swizzled (G4); m_lds padded to 36 floats/row (2-way max = free).
__global__ __launch_bounds__(256, 4) void fused_layer(
        const int* __restrict__ rp, const int* __restrict__ src,
        const float2* __restrict__ geo, const float2* __restrict__ tab2L,
        const float* __restrict__ hwin,
        const short* __restrict__ l2wT, const float* __restrict__ l2b,
        const short* __restrict__ lwT, const float* __restrict__ lb,
        float* __restrict__ h,
        const short* __restrict__ l1Tn, float* __restrict__ hwout) {
    __shared__ float m_lds[16][36];         // padded: bank-friendly b128 reads
    __shared__ short xs[16 * 128];          // 4 KB bf16, swizzled
    __shared__ short hs[16 * 128];          // 4 KB bf16, swizzled
    const int t   = threadIdx.x;
    const int w   = t >> 6;                 // wave 0..3
    const int l   = t & 63;
    const int lr  = l & 15;
    const int lg  = l >> 4;                 // k-group 0..3
    const int f   = l & 31;                 // feature lane (edge phase)
    const int par = l >> 5;                 // edge parity (edge phase)
    const int nb  = blockIdx.x << 4;        // 16 nodes per block
    const int ft0 = w * 2, ft1 = w * 2 + 1;

    // ---- issue-early (small): phase-A weights, biases, h-old (HBM)
    bf16x8 aw0 = *(const bf16x8*)(l2wT + (ft0 * 16 + lr) * 32 + lg * 8);
    bf16x8 aw1 = *(const bf16x8*)(l2wT + (ft1 * 16 + lr) * 32 + lg * 8);
    float biasA0 = l2b[ft0 * 16 + lr], biasA1 = l2b[ft1 * 16 + lr];
    float biasB0 = lb[ft0 * 16 + lr],  biasB1 = lb[ft1 * 16 + lr];
    float hold0[4], hold1[4];
    #pragma unroll
    for (int i = 0; i < 4; ++i) {
        hold0[i] = h[(size_t)(nb + lg * 4 + i) * HIDN + ft0 * 16 + lr];
        hold1[i] = h[(size_t)(nb + lg * 4 + i) * HIDN + ft1 * 16 + lr];
    }

    // ======== phase 1: edge aggregate, 4 interleaved chains per wave =======
    const int base = nb + w * 4;
    int r1q[4], eq[4];
    float accq[4];
    int maxtrip = 0;
    #pragma unroll
    for (int q = 0; q < 4; ++q) {
        int r0 = rp[base + q], r1 = rp[base + q + 1];
        r1q[q] = r1; eq[q] = r0 + par; accq[q] = 0.0f;
        int tq = (r1 - r0 + 1) >> 1;
        maxtrip = (tq > maxtrip) ? tq : maxtrip;
    }
    for (int it = 0; it < maxtrip; ++it) {
        #pragma unroll
        for (int q = 0; q < 4; ++q) {
            int e = eq[q];
            if (e < r1q[q]) {
                int s_ = src[e];
                float2 g_ = geo[e];
                float p_ = g_.x;
                int i0_ = (int)p_;
                i0_ = (i0_ > TABN - 2) ? (TABN - 2) : i0_;
                float fr_ = p_ - (float)i0_;
                float2 tv = tab2L[(size_t)i0_ * NFT + f];
                float w_ = fmaf(fr_, tv.y - tv.x, tv.x);
                accq[q] = fmaf(hwin[(size_t)s_ * NFT + f], w_ * g_.y, accq[q]);
            }
            eq[q] = e + 2;
        }
    }
    #pragma unroll
    for (int q = 0; q < 4; ++q) {
        float a = accq[q] + __shfl_xor(accq[q], 32);
        if (par == 0) m_lds[w * 4 + q][f] = a;
    }

    // ---- issue bulky weights now: latency hides under barrier + phase A
    bf16x8 bw0[4], bw1[4];
    #pragma unroll
    for (int ks = 0; ks < 4; ++ks) {
        bw0[ks] = *(const bf16x8*)(lwT + (ft0 * 16 + lr) * 128 + ks * 32 + lg * 8);
        bw1[ks] = *(const bf16x8*)(lwT + (ft1 * 16 + lr) * 128 + ks * 32 + lg * 8);
    }
    bf16x8 cw[4];
    if (l1Tn != nullptr && w < 2) {
        #pragma unroll
        for (int ks = 0; ks < 4; ++ks)
            cw[ks] = *(const bf16x8*)(l1Tn + (w * 16 + lr) * 128 + ks * 32 + lg * 8);
    }
    __syncthreads();

    // ======== phase A: x = ssp(m @ l2w + l2b) ========
    bf16x8 ma;
    {
        f32x4 m0 = *(const f32x4*)(&m_lds[lr][lg * 8]);
        f32x4 m1 = *(const f32x4*)(&m_lds[lr][lg * 8 + 4]);
        ma[0] = f2bf(m0.x); ma[1] = f2bf(m0.y); ma[2] = f2bf(m0.z); ma[3] = f2bf(m0.w);
        ma[4] = f2bf(m1.x); ma[5] = f2bf(m1.y); ma[6] = f2bf(m1.z); ma[7] = f2bf(m1.w);
    }
    f32x4 cA0 = {0.f, 0.f, 0.f, 0.f}, cA1 = {0.f, 0.f, 0.f, 0.f};
    cA0 = __builtin_amdgcn_mfma_f32_16x16x32_bf16(ma, aw0, cA0, 0, 0, 0);
    cA1 = __builtin_amdgcn_mfma_f32_16x16x32_bf16(ma, aw1, cA1, 0, 0, 0);
    #pragma unroll
    for (int i = 0; i < 4; ++i) {
        int row = lg * 4 + i;
        int col0 = ft0 * 16 + lr;
        int col1 = ft1 * 16 + lr;
        xs[row * 128 + ((col0 >> 3) ^ (row & 7)) * 8 + (col0 & 7)] = f2bf(ssp(cA0[i] + biasA0));
        xs[row * 128 + ((col1 >> 3) ^ (row & 7)) * 8 + (col1 & 7)] = f2bf(ssp(cA1[i] + biasA1));
    }
    __syncthreads();

    // ======== phase B: h += x @ lw + lb  (K = 128) ========
    bf16x8 xa[4];
    #pragma unroll
    for (int ks = 0; ks < 4; ++ks)
        xa[ks] = *(const bf16x8*)(xs + lr * 128 + ((ks * 4 + lg) ^ (lr & 7)) * 8);
    f32x4 cB0 = {0.f, 0.f, 0.f, 0.f}, cB1 = {0.f, 0.f, 0.f, 0.f};
    #pragma unroll
    for (int ks = 0; ks < 4; ++ks)
        cB0 = __builtin_amdgcn_mfma_f32_16x16x32_bf16(xa[ks], bw0[ks], cB0, 0, 0, 0);
    #pragma unroll
    for (int ks = 0; ks < 4; ++ks)
        cB1 = __builtin_amdgcn_mfma_f32_16x16x32_bf16(xa[ks], bw1[ks], cB1, 0, 0, 0);
    #pragma unroll
    for (int i = 0; i < 4; ++i) {
        int node = nb + lg * 4 + i;
        int row = lg * 4 + i;
        float hv0 = hold0[i] + cB0[i] + biasB0;
        float hv1 = hold1[i] + cB1[i] + biasB1;
        h[(size_t)node * HIDN + ft0 * 16 + lr] = hv0;
        h[(size_t)node * HIDN + ft1 * 16 + lr] = hv1;
        int col0 = ft0 * 16 + lr;
        int col1 = ft1 * 16 + lr;
        hs[row * 128 + ((col0 >> 3) ^ (row & 7)) * 8 + (col0 & 7)] = f2bf(hv0);
        hs[row * 128 + ((col1 >> 3) ^ (row & 7)) * 8 + (col1 & 7)] = f2bf(hv1);
    }

    // ======== phase C: hw_next = h_new @ l1[l+1]  (ping-pong buffer) ========
    if (l1Tn != nullptr) {
        __syncthreads();
        if (w < 2) {
            bf16x8 ha[4];
            #pragma unroll
            for (int ks = 0; ks < 4; ++ks)
                ha[ks] = *(const bf16x8*)(hs + lr * 128 + ((ks * 4 + lg) ^ (lr & 7)) * 8);
            f32x4 c = {0.f, 0.f, 0.f, 0.f};
            #pragma unroll
            for (int ks = 0; ks < 4; ++ks)
                c = __builtin_amdgcn_mfma_f32_16x16x32_bf16(ha[ks], cw[ks], c, 0, 0, 0);
            #pragma unroll
            for (int i = 0; i < 4; ++i) {
                int node = nb + lg * 4 + i;
                hwout[(size_t)node * NFT + w * 16 + lr] = c[i];
            }
        }
    }
}

// ---------------------------------------------------------------------------
extern "C" void kernel_launch(void* const* d_in, const int* in_sizes, int n_in,
                              void* d_out, int out_size, void* d_ws, size_t ws_size,
                              hipStream_t stream) {
    const int*   z    = (const int*)d_in[0];
    const float* pos  = (const float*)d_in[1];
    const int*   ei   = (const int*)d_in[2];    // [2][E]
    const float* mask = (const float*)d_in[3];
    const float* emb  = (const float*)d_in[4];
    const float* w1   = (const float*)d_in[5];  // [6][50][32]
    const float* b1   = (const float*)d_in[6];  // [6][32]
    const float* w2   = (const float*)d_in[7];  // [6][32][32]
    const float* b2   = (const float*)d_in[8];  // [6][32]
    const float* l1w  = (const float*)d_in[9];  // [6][128][32]
    const float* l2w  = (const float*)d_in[10]; // [6][32][128]
    const float* l2b  = (const float*)d_in[11]; // [6][128]
    const float* lww  = (const float*)d_in[12]; // [6][128][128]
    const float* lbb  = (const float*)d_in[13]; // [6][128]
    float* h = (float*)d_out;

    char* base = (char*)d_ws;
    size_t o = 0;
    auto alloc = [&](size_t bytes) -> void* {
        void* p = base + o;
        o += (bytes + 255) & ~(size_t)255;
        return p;
    };
    int*    d_rp   = (int*)alloc((NN + 1) * sizeof(int));
    float2* d_geo  = (float2*)alloc((size_t)EE * sizeof(float2));
    float*  d_tab  = (float*)alloc((size_t)NLAY * TABN * NFT * sizeof(float));
    float2* d_tab2 = (float2*)alloc((size_t)NLAY * TABN * NFT * sizeof(float2));
    float*  d_hwA  = (float*)alloc((size_t)NN * NFT * sizeof(float));
    float*  d_hwB  = (float*)alloc((size_t)NN * NFT * sizeof(float));
    short*  d_l2wT = (short*)alloc((size_t)NLAY * 4096 * sizeof(short));
    short*  d_lwT  = (short*)alloc((size_t)NLAY * 16384 * sizeof(short));
    short*  d_l1T  = (short*)alloc((size_t)NLAY * 4096 * sizeof(short));
    (void)ws_size; (void)in_sizes; (void)n_in; (void)out_size;

    prep_weights<<<(NLAY * 24576 + 255) / 256, 256, 0, stream>>>(
        l2w, lww, l1w, d_l2wT, d_lwT, d_l1T);
    build_rowptr<<<(NN + 1 + 255) / 256, 256, 0, stream>>>(ei + EE, mask, d_rp);
    edge_geom<<<(EE + 255) / 256, 256, 0, stream>>>(ei, pos, mask, d_geo);
    tab_kernel<<<NLAY * TABN / 8, 256, 0, stream>>>(w1, b1, w2, b2, d_tab);
    pack_tab2<<<(NLAY * TABN * NFT + 255) / 256, 256, 0, stream>>>(d_tab, d_tab2);
    init_h<<<NN * 32 / 256, 256, 0, stream>>>(z, (const float4*)emb, (float4*)h);
    hw_kernel<<<NN / 8, 256, 0, stream>>>(h, l1w, d_hwA);   // layer-0 hw (f32)

    for (int l = 0; l < NLAY; ++l) {
        const float* hwin  = (l & 1) ? d_hwB : d_hwA;
        float*       hwout = (l & 1) ? d_hwA : d_hwB;
        const short* l1Tn  = (l + 1 < NLAY) ? (d_l1T + (size_t)(l + 1) * 4096) : nullptr;
        fused_layer<<<NN / 16, 256, 0, stream>>>(
            d_rp, ei, d_geo, d_tab2 + (size_t)l * TABN * NFT, hwin,
            d_l2wT + (size_t)l * 4096, l2b + (size_t)l * HIDN,
            d_lwT + (size_t)l * 16384, lbb + (size_t)l * HIDN, h, l1Tn, hwout);
    }
}

// Round 8
// 230.965 us; speedup vs baseline: 1.5945x; 1.5945x over previous
//
#include <hip/hip_runtime.h>
#include <math.h>

#define NN     16384
#define EE     600000
#define HIDN   128
#define NFT    32
#define NGAUSS 50
#define NLAY   6
#define TABN   8192
#define CUTF   10.0f

typedef float f32x4  __attribute__((ext_vector_type(4)));
typedef short bf16x8 __attribute__((ext_vector_type(8)));

__device__ __forceinline__ float ssp(float x) {
    // softplus(x) - log(2), numerically stable
    return fmaxf(x, 0.0f) + log1pf(__expf(-fabsf(x))) - 0.69314718055994531f;
}

__device__ __forceinline__ short f2bf(float x) {
    // f32 -> bf16 round-to-nearest-even
    union { float f; unsigned u; } v; v.f = x;
    unsigned r = v.u + 0x7fffu + ((v.u >> 16) & 1u);
    return (short)(r >> 16);
}

__device__ __forceinline__ float bf2f(unsigned u16) {
    union { unsigned u; float f; } v; v.u = u16 << 16;
    return v.f;
}

// ---------------------------------------------------------------- row_ptr ---
// Real edges (mask>0.5) are a prefix with dst ascending; padding after.
// key(e) = real ? dst[e] : INT_MAX is monotone -> per-thread lower_bound.
__global__ void build_rowptr(const int* __restrict__ dst, const float* __restrict__ mask,
                             int* __restrict__ rp) {
    int n = blockIdx.x * blockDim.x + threadIdx.x;
    if (n > NN) return;
    int lo = 0, hi = EE;
    while (lo < hi) {
        int mid = (lo + hi) >> 1;
        int key = (mask[mid] > 0.5f) ? dst[mid] : 0x7fffffff;
        if (key < n) lo = mid + 1; else hi = mid;
    }
    rp[n] = lo;
}

// ------------------------------------------------------------- edge geom ----
// geo[e] = (d * TABSCALE, cutoff_coeff)
__global__ void edge_geom(const int* __restrict__ ei, const float* __restrict__ pos,
                          const float* __restrict__ mask, float2* __restrict__ geo) {
    int e = blockIdx.x * blockDim.x + threadIdx.x;
    if (e >= EE) return;
    int s = ei[e], t = ei[EE + e];
    float dx = pos[s * 3 + 0] - pos[t * 3 + 0];
    float dy = pos[s * 3 + 1] - pos[t * 3 + 1];
    float dz = pos[s * 3 + 2] - pos[t * 3 + 2];
    float d = sqrtf(dx * dx + dy * dy + dz * dz);
    float cc = 0.5f * (cosf(d * 0.31415926535897932f) + 1.0f) * mask[e];
    geo[e] = make_float2(d * ((TABN - 1) / CUTF), cc);
}

// ----------------------------------------------------------- table build ----
// Writes the PACKED bf16-pair table directly:
//   tab2b[l][ent][f] = u32( bf16 W[ent][f] | bf16 W[ent+1][f] << 16 )
// entry (l,ent,f) stores its own value into slot .x of ent and slot .y of
// ent-1 (2B stores).
__global__ void tab_kernel(const float* __restrict__ w1, const float* __restrict__ b1,
                           const float* __restrict__ w2, const float* __restrict__ b2,
                           unsigned short* __restrict__ tab2b) {
    __shared__ float ea[8][NGAUSS];
    __shared__ float t1[8][NFT];
    int t = threadIdx.x, f = t & 31, g = t >> 5;
    int id = blockIdx.x * 8 + g;           // 0 .. NLAY*TABN-1 exact
    int l = id / TABN, ent = id % TABN;
    float d = ent * (CUTF / (TABN - 1));
    const float delta = CUTF / (NGAUSS - 1);
    const float coeff = -0.5f / (delta * delta);
    for (int gg = f; gg < NGAUSS; gg += 32) {
        float diff = d - gg * delta;
        ea[g][gg] = __expf(coeff * diff * diff);
    }
    __syncthreads();
    float a = b1[l * NFT + f];
    const float* w1l = w1 + l * NGAUSS * NFT;
    #pragma unroll
    for (int gg = 0; gg < NGAUSS; ++gg)
        a = fmaf(ea[g][gg], w1l[gg * NFT + f], a);
    t1[g][f] = ssp(a);
    __syncthreads();
    float c = b2[l * NFT + f];
    const float* w2l = w2 + l * NFT * NFT;
    #pragma unroll
    for (int k = 0; k < NFT; ++k)
        c = fmaf(t1[g][k], w2l[k * NFT + f], c);
    unsigned short cb = (unsigned short)f2bf(c);
    size_t idx = (size_t)id * NFT + f;
    tab2b[2 * idx] = cb;                             // .x of ent
    if (ent > 0)        tab2b[2 * (idx - NFT) + 1] = cb;  // .y of ent-1
    if (ent == TABN - 1) tab2b[2 * idx + 1] = cb;         // clamp top
}

// ---------------------------------------------------------------- init h ----
__global__ void init_h(const int* __restrict__ z, const float4* __restrict__ emb4,
                       float4* __restrict__ h4) {
    int tid = blockIdx.x * blockDim.x + threadIdx.x;   // N*32 threads
    int n = tid >> 5, c = tid & 31;
    h4[tid] = emb4[(size_t)z[n] * 32 + c];
}

// --------------------------------------------------------- weight prep ------
//  l2wT[l][f<128][k<32]  = l2w[l][k][f]
//  lwT [l][f<128][k<128] = lw [l][k][f]
//  l1T [l][f<32 ][k<128] = l1 [l][k][f]
__global__ void prep_weights(const float* __restrict__ l2w, const float* __restrict__ lww,
                             const float* __restrict__ l1w,
                             short* __restrict__ l2wT, short* __restrict__ lwT,
                             short* __restrict__ l1T) {
    const int per = 4096 + 16384 + 4096;   // 24576 per layer
    int id = blockIdx.x * blockDim.x + threadIdx.x;
    if (id >= NLAY * per) return;
    int l = id / per, r = id % per;
    if (r < 4096) {
        int f = r >> 5, k = r & 31;
        l2wT[l * 4096 + f * 32 + k] = f2bf(l2w[l * 4096 + k * 128 + f]);
    } else if (r < 4096 + 16384) {
        int q = r - 4096; int f = q >> 7, k = q & 127;
        lwT[l * 16384 + f * 128 + k] = f2bf(lww[l * 16384 + k * 128 + f]);
    } else {
        int q = r - 20480; int f = q >> 7, k = q & 127;   // f<32, k<128
        l1T[l * 4096 + f * 128 + k] = f2bf(l1w[l * 4096 + k * 32 + f]);
    }
}

// ------------------------------------------------- hw = h@l1 (layer 0) ------
// Output bf16.
__global__ void hw_kernel(const float* __restrict__ h, const float* __restrict__ l1,
                          unsigned short* __restrict__ hw) {
    __shared__ float l1s[HIDN * NFT];
    int t = threadIdx.x, f = t & 31, nl = t >> 5;
    for (int i = t; i < HIDN * NFT / 4; i += 256)
        ((float4*)l1s)[i] = ((const float4*)l1)[i];
    __syncthreads();
    int n = blockIdx.x * 8 + nl;
    const float4* h4 = (const float4*)(h + (size_t)n * HIDN);
    float acc = 0.0f;
    #pragma unroll
    for (int k4 = 0; k4 < 32; ++k4) {
        float4 hv = h4[k4];
        acc = fmaf(hv.x, l1s[(k4 * 4 + 0) * NFT + f], acc);
        acc = fmaf(hv.y, l1s[(k4 * 4 + 1) * NFT + f], acc);
        acc = fmaf(hv.z, l1s[(k4 * 4 + 2) * NFT + f], acc);
        acc = fmaf(hv.w, l1s[(k4 * 4 + 3) * NFT + f], acc);
    }
    hw[(size_t)n * NFT + f] = (unsigned short)f2bf(acc);
}

// -------------------------------------------------- edge aggregate (CSR) ----
// One 64-lane wave per dst node: lane = (par, f); parity-split over edges,
// combined with shfl_xor(32). 2x unroll. bf16 table pair (one u32 load) +
// bf16 hw -> ~halved L2 bytes and one less dependent hop vs f32 version.
// Output m in bf16 (it feeds the MFMA A-operand, which is bf16 anyway).
#define EDGE_BODY(EIDX)                                                    \
    {                                                                      \
        int e_ = (EIDX);                                                   \
        int s_ = src[e_];                                                  \
        float2 g_ = geo[e_];                                               \
        float p_ = g_.x;                                                   \
        int i0_ = (int)p_;                                                 \
        i0_ = (i0_ > TABN - 2) ? (TABN - 2) : i0_;                         \
        float fr_ = p_ - (float)i0_;                                       \
        unsigned tv_ = tabL[(size_t)i0_ * NFT + f];                        \
        float w0_ = bf2f(tv_ & 0xffffu);                                   \
        float w1_ = bf2f(tv_ >> 16);                                       \
        float w_ = fmaf(fr_, w1_ - w0_, w0_);                              \
        float hv_ = bf2f(hw[(size_t)s_ * NFT + f]);                        \
        acc = fmaf(hv_, w_ * g_.y, acc);                                   \
    }

__global__ void edge_agg(const int* __restrict__ rp, const int* __restrict__ src,
                         const float2* __restrict__ geo, const unsigned* __restrict__ tabL,
                         const unsigned short* __restrict__ hw,
                         unsigned short* __restrict__ m) {
    int t = threadIdx.x;
    int f = t & 31, par = (t >> 5) & 1, g = t >> 6;   // 4 nodes / 256-thr block
    int n = blockIdx.x * 4 + g;
    int r0 = rp[n], r1 = rp[n + 1];
    float acc = 0.0f;
    int e = r0 + par;
    for (; e + 2 < r1; e += 4) {          // two independent bodies -> ILP
        EDGE_BODY(e);
        EDGE_BODY(e + 2);
    }
    if (e < r1) EDGE_BODY(e);
    acc += __shfl_xor(acc, 32);
    if (par == 0) m[(size_t)n * NFT + f] = (unsigned short)f2bf(acc);
}

// --------------------------------- node update, MFMA (+ fused next-layer hw)
// x = ssp(m@l2w + l2b); h += x@lw + lb; hw_next = h_new @ l1[l+1]
// 256 threads = 4 waves; block owns 16 nodes; wave w owns f-tile pair
// {2w, 2w+1}. Grid NN/16 = 1024 blocks -> 4 blocks/CU, 16 waves/CU.
// ISSUE-EARLY: all global operands loaded into named registers at entry so
// their latency overlaps once. __launch_bounds__(256,4): VGPR cap 128.
// m is bf16 -> A-frag is a direct 16B load (no per-lane cvt).
// mfma_f32_16x16x32_bf16 layouts (m89/m91-verified):
//   A: lane(16g+r) holds A[r][8g..8g+7];  B: lane(16g+c) holds B[8g..8g+7][c]
//   C/D: col = lane&15, row = 4*(lane>>4) + reg
// xs/hs tiles XOR-swizzled: 16B-granule ^= (row&7)  (G4).
__global__ __launch_bounds__(256, 4) void node_update_mfma(
        const unsigned short* __restrict__ mg, const short* __restrict__ l2wT,
        const float* __restrict__ l2b, const short* __restrict__ lwT,
        const float* __restrict__ lb, float* __restrict__ h,
        const short* __restrict__ l1Tn, unsigned short* __restrict__ hwn) {
    __shared__ short xs[16 * 128];          // 4 KB bf16, swizzled
    __shared__ short hs[16 * 128];          // 4 KB bf16, swizzled
    const int t   = threadIdx.x;
    const int w   = t >> 6;                 // wave 0..3
    const int l   = t & 63;
    const int lr  = l & 15;
    const int lg  = l >> 4;                 // k-group 0..3
    const int nb  = blockIdx.x << 4;        // 16 nodes per block
    const int ft0 = w * 2, ft1 = w * 2 + 1;

    // ======== issue-early: every global load this kernel needs ========
    bf16x8 ma = *(const bf16x8*)(mg + (size_t)(nb + lr) * NFT + lg * 8);
    bf16x8 aw0 = *(const bf16x8*)(l2wT + (ft0 * 16 + lr) * 32 + lg * 8);
    bf16x8 aw1 = *(const bf16x8*)(l2wT + (ft1 * 16 + lr) * 32 + lg * 8);
    bf16x8 bw0[4], bw1[4];
    #pragma unroll
    for (int ks = 0; ks < 4; ++ks) {
        bw0[ks] = *(const bf16x8*)(lwT + (ft0 * 16 + lr) * 128 + ks * 32 + lg * 8);
        bw1[ks] = *(const bf16x8*)(lwT + (ft1 * 16 + lr) * 128 + ks * 32 + lg * 8);
    }
    float hold0[4], hold1[4];
    #pragma unroll
    for (int i = 0; i < 4; ++i) {
        hold0[i] = h[(size_t)(nb + lg * 4 + i) * HIDN + ft0 * 16 + lr];
        hold1[i] = h[(size_t)(nb + lg * 4 + i) * HIDN + ft1 * 16 + lr];
    }
    float biasA0 = l2b[ft0 * 16 + lr], biasA1 = l2b[ft1 * 16 + lr];
    float biasB0 = lb[ft0 * 16 + lr],  biasB1 = lb[ft1 * 16 + lr];

    // ======== phase A: x = ssp(m @ l2w + l2b) ========
    f32x4 cA0 = {0.f, 0.f, 0.f, 0.f}, cA1 = {0.f, 0.f, 0.f, 0.f};
    cA0 = __builtin_amdgcn_mfma_f32_16x16x32_bf16(ma, aw0, cA0, 0, 0, 0);
    cA1 = __builtin_amdgcn_mfma_f32_16x16x32_bf16(ma, aw1, cA1, 0, 0, 0);
    #pragma unroll
    for (int i = 0; i < 4; ++i) {
        int row = lg * 4 + i;
        int col0 = ft0 * 16 + lr;
        int col1 = ft1 * 16 + lr;
        xs[row * 128 + ((col0 >> 3) ^ (row & 7)) * 8 + (col0 & 7)] = f2bf(ssp(cA0[i] + biasA0));
        xs[row * 128 + ((col1 >> 3) ^ (row & 7)) * 8 + (col1 & 7)] = f2bf(ssp(cA1[i] + biasA1));
    }
    // issue phase-C weights while waiting at the barrier
    bf16x8 cw[4];
    if (l1Tn != nullptr && w < 2) {
        #pragma unroll
        for (int ks = 0; ks < 4; ++ks)
            cw[ks] = *(const bf16x8*)(l1Tn + (w * 16 + lr) * 128 + ks * 32 + lg * 8);
    }
    __syncthreads();

    // ======== phase B: h += x @ lw + lb  (K = 128) ========
    bf16x8 xa[4];
    #pragma unroll
    for (int ks = 0; ks < 4; ++ks)
        xa[ks] = *(const bf16x8*)(xs + lr * 128 + ((ks * 4 + lg) ^ (lr & 7)) * 8);
    f32x4 cB0 = {0.f, 0.f, 0.f, 0.f}, cB1 = {0.f, 0.f, 0.f, 0.f};
    #pragma unroll
    for (int ks = 0; ks < 4; ++ks)
        cB0 = __builtin_amdgcn_mfma_f32_16x16x32_bf16(xa[ks], bw0[ks], cB0, 0, 0, 0);
    #pragma unroll
    for (int ks = 0; ks < 4; ++ks)
        cB1 = __builtin_amdgcn_mfma_f32_16x16x32_bf16(xa[ks], bw1[ks], cB1, 0, 0, 0);
    #pragma unroll
    for (int i = 0; i < 4; ++i) {
        int node = nb + lg * 4 + i;
        int row = lg * 4 + i;
        float hv0 = hold0[i] + cB0[i] + biasB0;
        float hv1 = hold1[i] + cB1[i] + biasB1;
        h[(size_t)node * HIDN + ft0 * 16 + lr] = hv0;
        h[(size_t)node * HIDN + ft1 * 16 + lr] = hv1;
        int col0 = ft0 * 16 + lr;
        int col1 = ft1 * 16 + lr;
        hs[row * 128 + ((col0 >> 3) ^ (row & 7)) * 8 + (col0 & 7)] = f2bf(hv0);
        hs[row * 128 + ((col1 >> 3) ^ (row & 7)) * 8 + (col1 & 7)] = f2bf(hv1);
    }

    // ======== phase C: fused next-layer hw = h_new @ l1[l+1] (bf16 out) ====
    if (l1Tn != nullptr) {
        __syncthreads();
        if (w < 2) {
            bf16x8 ha[4];
            #pragma unroll
            for (int ks = 0; ks < 4; ++ks)
                ha[ks] = *(const bf16x8*)(hs + lr * 128 + ((ks * 4 + lg) ^ (lr & 7)) * 8);
            f32x4 c = {0.f, 0.f, 0.f, 0.f};
            #pragma unroll
            for (int ks = 0; ks < 4; ++ks)
                c = __builtin_amdgcn_mfma_f32_16x16x32_bf16(ha[ks], cw[ks], c, 0, 0, 0);
            #pragma unroll
            for (int i = 0; i < 4; ++i) {
                int node = nb + lg * 4 + i;
                hwn[(size_t)node * NFT + w * 16 + lr] = (unsigned short)f2bf(c[i]);
            }
        }
    }
}

// ---------------------------------------------------------------------------
extern "C" void kernel_launch(void* const* d_in, const int* in_sizes, int n_in,
                              void* d_out, int out_size, void* d_ws, size_t ws_size,
                              hipStream_t stream) {
    const int*   z    = (const int*)d_in[0];
    const float* pos  = (const float*)d_in[1];
    const int*   ei   = (const int*)d_in[2];    // [2][E]
    const float* mask = (const float*)d_in[3];
    const float* emb  = (const float*)d_in[4];
    const float* w1   = (const float*)d_in[5];  // [6][50][32]
    const float* b1   = (const float*)d_in[6];  // [6][32]
    const float* w2   = (const float*)d_in[7];  // [6][32][32]
    const float* b2   = (const float*)d_in[8];  // [6][32]
    const float* l1w  = (const float*)d_in[9];  // [6][128][32]
    const float* l2w  = (const float*)d_in[10]; // [6][32][128]
    const float* l2b  = (const float*)d_in[11]; // [6][128]
    const float* lww  = (const float*)d_in[12]; // [6][128][128]
    const float* lbb  = (const float*)d_in[13]; // [6][128]
    float* h = (float*)d_out;

    char* base = (char*)d_ws;
    size_t o = 0;
    auto alloc = [&](size_t bytes) -> void* {
        void* p = base + o;
        o += (bytes + 255) & ~(size_t)255;
        return p;
    };
    int*            d_rp    = (int*)alloc((NN + 1) * sizeof(int));
    float2*         d_geo   = (float2*)alloc((size_t)EE * sizeof(float2));
    unsigned short* d_tab2b = (unsigned short*)alloc((size_t)NLAY * TABN * NFT * 2 * sizeof(unsigned short));
    unsigned short* d_hwA   = (unsigned short*)alloc((size_t)NN * NFT * sizeof(unsigned short));
    unsigned short* d_hwB   = (unsigned short*)alloc((size_t)NN * NFT * sizeof(unsigned short));
    unsigned short* d_m     = (unsigned short*)alloc((size_t)NN * NFT * sizeof(unsigned short));
    short*          d_l2wT  = (short*)alloc((size_t)NLAY * 4096 * sizeof(short));
    short*          d_lwT   = (short*)alloc((size_t)NLAY * 16384 * sizeof(short));
    short*          d_l1T   = (short*)alloc((size_t)NLAY * 4096 * sizeof(short));
    (void)ws_size; (void)in_sizes; (void)n_in; (void)out_size;

    prep_weights<<<(NLAY * 24576 + 255) / 256, 256, 0, stream>>>(
        l2w, lww, l1w, d_l2wT, d_lwT, d_l1T);
    build_rowptr<<<(NN + 1 + 255) / 256, 256, 0, stream>>>(ei + EE, mask, d_rp);
    edge_geom<<<(EE + 255) / 256, 256, 0, stream>>>(ei, pos, mask, d_geo);
    tab_kernel<<<NLAY * TABN / 8, 256, 0, stream>>>(w1, b1, w2, b2, d_tab2b);
    init_h<<<NN * 32 / 256, 256, 0, stream>>>(z, (const float4*)emb, (float4*)h);
    hw_kernel<<<NN / 8, 256, 0, stream>>>(h, l1w, d_hwA);   // layer-0 hw (bf16)

    for (int l = 0; l < NLAY; ++l) {
        const unsigned short* hwin  = (l & 1) ? d_hwB : d_hwA;
        unsigned short*       hwout = (l & 1) ? d_hwA : d_hwB;
        const short* l1Tn = (l + 1 < NLAY) ? (d_l1T + (size_t)(l + 1) * 4096) : nullptr;
        edge_agg<<<NN / 4, 256, 0, stream>>>(
            d_rp, ei, d_geo, (const unsigned*)(d_tab2b + (size_t)l * TABN * NFT * 2),
            hwin, d_m);
        node_update_mfma<<<NN / 16, 256, 0, stream>>>(
            d_m, d_l2wT + (size_t)l * 4096, l2b + (size_t)l * HIDN,
            d_lwT + (size_t)l * 16384, lbb + (size_t)l * HIDN, h, l1Tn, hwout);
    }
}

// Round 9
// 205.195 us; speedup vs baseline: 1.7948x; 1.1256x over previous
//
#include <hip/hip_runtime.h>
#include <math.h>

#define NN     16384
#define EE     600000
#define HIDN   128
#define NFT    32
#define NGAUSS 50
#define NLAY   6
#define TABN   8192
#define CUTF   10.0f

typedef float f32x4  __attribute__((ext_vector_type(4)));
typedef short bf16x8 __attribute__((ext_vector_type(8)));

__device__ __forceinline__ float ssp(float x) {
    // softplus(x) - log(2), numerically stable
    return fmaxf(x, 0.0f) + log1pf(__expf(-fabsf(x))) - 0.69314718055994531f;
}

__device__ __forceinline__ short f2bf(float x) {
    // f32 -> bf16 round-to-nearest-even
    union { float f; unsigned u; } v; v.f = x;
    unsigned r = v.u + 0x7fffu + ((v.u >> 16) & 1u);
    return (short)(r >> 16);
}

__device__ __forceinline__ float bf2f(unsigned u16) {
    union { unsigned u; float f; } v; v.u = u16 << 16;
    return v.f;
}

// ===================== merged setup kernel (block-range dispatch) ==========
// blocks [0, NB_TAB)               : tab build (packed bf16 pairs)
// blocks [NB_TAB, +NB_GEO)         : edge geom
// blocks [.., +NB_RP)              : row_ptr binary search
// blocks [.., +NB_PREP)            : weight transpose+bf16
#define NB_TAB  (NLAY * TABN / 8)                   // 6144
#define NB_GEO  ((EE + 255) / 256)                  // 2344
#define NB_RP   ((NN + 1 + 255) / 256)              // 65
#define NB_PREP ((NLAY * 24576 + 255) / 256)        // 576

__global__ void setup_kernel(
        const float* __restrict__ w1, const float* __restrict__ b1,
        const float* __restrict__ w2, const float* __restrict__ b2,
        unsigned short* __restrict__ tab2b,
        const int* __restrict__ ei, const float* __restrict__ pos,
        const float* __restrict__ mask, float2* __restrict__ geo,
        int* __restrict__ rp,
        const float* __restrict__ l2w, const float* __restrict__ lww,
        const float* __restrict__ l1w,
        short* __restrict__ l2wT, short* __restrict__ lwT,
        short* __restrict__ l1T) {
    __shared__ float ea[8][NGAUSS];
    __shared__ float t1[8][NFT];
    const int b = blockIdx.x;
    const int t = threadIdx.x;

    if (b < NB_TAB) {
        // ------- tab: tab2b[l][ent][f] = (bf16 W[ent][f], bf16 W[ent+1][f])
        int f = t & 31, g = t >> 5;
        int id = b * 8 + g;                 // 0 .. NLAY*TABN-1 exact
        int l = id / TABN, ent = id % TABN;
        float d = ent * (CUTF / (TABN - 1));
        const float delta = CUTF / (NGAUSS - 1);
        const float coeff = -0.5f / (delta * delta);
        for (int gg = f; gg < NGAUSS; gg += 32) {
            float diff = d - gg * delta;
            ea[g][gg] = __expf(coeff * diff * diff);
        }
        __syncthreads();
        float a = b1[l * NFT + f];
        const float* w1l = w1 + l * NGAUSS * NFT;
        #pragma unroll
        for (int gg = 0; gg < NGAUSS; ++gg)
            a = fmaf(ea[g][gg], w1l[gg * NFT + f], a);
        t1[g][f] = ssp(a);
        __syncthreads();
        float c = b2[l * NFT + f];
        const float* w2l = w2 + l * NFT * NFT;
        #pragma unroll
        for (int k = 0; k < NFT; ++k)
            c = fmaf(t1[g][k], w2l[k * NFT + f], c);
        unsigned short cb = (unsigned short)f2bf(c);
        size_t idx = (size_t)id * NFT + f;
        tab2b[2 * idx] = cb;                                  // .x of ent
        if (ent > 0)         tab2b[2 * (idx - NFT) + 1] = cb; // .y of ent-1
        if (ent == TABN - 1) tab2b[2 * idx + 1] = cb;         // clamp top
    } else if (b < NB_TAB + NB_GEO) {
        // ------- edge geom: geo[e] = (d * TABSCALE, cutoff_coeff)
        int e = (b - NB_TAB) * 256 + t;
        if (e >= EE) return;
        int s = ei[e], d2 = ei[EE + e];
        float dx = pos[s * 3 + 0] - pos[d2 * 3 + 0];
        float dy = pos[s * 3 + 1] - pos[d2 * 3 + 1];
        float dz = pos[s * 3 + 2] - pos[d2 * 3 + 2];
        float d = sqrtf(dx * dx + dy * dy + dz * dz);
        float cc = 0.5f * (cosf(d * 0.31415926535897932f) + 1.0f) * mask[e];
        geo[e] = make_float2(d * ((TABN - 1) / CUTF), cc);
    } else if (b < NB_TAB + NB_GEO + NB_RP) {
        // ------- row_ptr: key(e) = real ? dst[e] : INT_MAX, lower_bound
        int n = (b - NB_TAB - NB_GEO) * 256 + t;
        if (n > NN) return;
        const int* dst = ei + EE;
        int lo = 0, hi = EE;
        while (lo < hi) {
            int mid = (lo + hi) >> 1;
            int key = (mask[mid] > 0.5f) ? dst[mid] : 0x7fffffff;
            if (key < n) lo = mid + 1; else hi = mid;
        }
        rp[n] = lo;
    } else {
        // ------- weight transpose + bf16
        const int per = 4096 + 16384 + 4096;   // 24576 per layer
        int id = (b - NB_TAB - NB_GEO - NB_RP) * 256 + t;
        if (id >= NLAY * per) return;
        int l = id / per, r = id % per;
        if (r < 4096) {
            int f = r >> 5, k = r & 31;
            l2wT[l * 4096 + f * 32 + k] = f2bf(l2w[l * 4096 + k * 128 + f]);
        } else if (r < 4096 + 16384) {
            int q = r - 4096; int f = q >> 7, k = q & 127;
            lwT[l * 16384 + f * 128 + k] = f2bf(lww[l * 16384 + k * 128 + f]);
        } else {
            int q = r - 20480; int f = q >> 7, k = q & 127;   // f<32, k<128
            l1T[l * 4096 + f * 128 + k] = f2bf(l1w[l * 4096 + k * 32 + f]);
        }
    }
}

// ================= init h = emb[z] AND hw = h @ l1[0] (fused) ==============
// 8 nodes / 256-thr block. l1[0] staged f32 in LDS; h rows staged in LDS.
__global__ void init_h_hw(const int* __restrict__ z, const float4* __restrict__ emb4,
                          const float* __restrict__ l1w,
                          float4* __restrict__ h4, unsigned short* __restrict__ hw) {
    __shared__ float l1s[HIDN * NFT];       // 16 KB
    __shared__ float hls[8][HIDN];          // 4 KB
    int t = threadIdx.x, c = t & 31, nl = t >> 5;
    for (int i = t; i < HIDN * NFT / 4; i += 256)
        ((float4*)l1s)[i] = ((const float4*)l1w)[i];
    int node = blockIdx.x * 8 + nl;
    float4 hv = emb4[(size_t)z[node] * 32 + c];
    h4[(size_t)node * 32 + c] = hv;
    *(float4*)(&hls[nl][c * 4]) = hv;
    __syncthreads();
    // hw[node][f] = sum_k h[node][k] * l1[k][f]   (thread = (nl, f))
    float acc = 0.0f;
    #pragma unroll 16
    for (int k = 0; k < HIDN; ++k)
        acc = fmaf(hls[nl][k], l1s[k * NFT + c], acc);
    hw[(size_t)node * NFT + c] = (unsigned short)f2bf(acc);
}

// -------------------------------------------------- edge aggregate (CSR) ----
// One 64-lane wave per dst node: lane = (par, f); parity split + 4 unrolled
// independent bodies (e, e+2, e+4, e+6 step 8) = 4 concurrent 2-hop L2
// chains per lane (r8 had only 2 -> latency-bound). Two accumulators.
// bf16 packed table pair (one u32 load) + bf16 hw.
#define EDGE_BODY(EIDX, ACC)                                               \
    {                                                                      \
        int e_ = (EIDX);                                                   \
        int s_ = src[e_];                                                  \
        float2 g_ = geo[e_];                                               \
        float p_ = g_.x;                                                   \
        int i0_ = (int)p_;                                                 \
        i0_ = (i0_ > TABN - 2) ? (TABN - 2) : i0_;                         \
        float fr_ = p_ - (float)i0_;                                       \
        unsigned tv_ = tabL[(size_t)i0_ * NFT + f];                        \
        float w0_ = bf2f(tv_ & 0xffffu);                                   \
        float w1_ = bf2f(tv_ >> 16);                                       \
        float w_ = fmaf(fr_, w1_ - w0_, w0_);                              \
        float hv_ = bf2f(hw[(size_t)s_ * NFT + f]);                        \
        ACC = fmaf(hv_, w_ * g_.y, ACC);                                   \
    }

__global__ void edge_agg(const int* __restrict__ rp, const int* __restrict__ src,
                         const float2* __restrict__ geo, const unsigned* __restrict__ tabL,
                         const unsigned short* __restrict__ hw,
                         unsigned short* __restrict__ m) {
    int t = threadIdx.x;
    int f = t & 31, par = (t >> 5) & 1, g = t >> 6;   // 4 nodes / 256-thr block
    int n = blockIdx.x * 4 + g;
    int r0 = rp[n], r1 = rp[n + 1];
    float acc0 = 0.0f, acc1 = 0.0f;
    int e = r0 + par;
    for (; e + 6 < r1; e += 8) {          // 4 independent chains
        EDGE_BODY(e,     acc0);
        EDGE_BODY(e + 2, acc1);
        EDGE_BODY(e + 4, acc0);
        EDGE_BODY(e + 6, acc1);
    }
    for (; e + 2 < r1; e += 4) {          // tail, 2 chains
        EDGE_BODY(e,     acc0);
        EDGE_BODY(e + 2, acc1);
    }
    if (e < r1) EDGE_BODY(e, acc0);
    float acc = acc0 + acc1;
    acc += __shfl_xor(acc, 32);
    if (par == 0) m[(size_t)n * NFT + f] = (unsigned short)f2bf(acc);
}

// --------------------------------- node update, MFMA (+ fused next-layer hw)
// x = ssp(m@l2w + l2b); h += x@lw + lb; hw_next = h_new @ l1[l+1]
// 256 threads = 4 waves; block owns 16 nodes; wave w owns f-tile pair
// {2w, 2w+1}. Grid NN/16 = 1024 blocks -> 4 blocks/CU, 16 waves/CU.
// ISSUE-EARLY operands; __launch_bounds__(256,4) keeps VGPR cap at 128.
// mfma_f32_16x16x32_bf16 layouts (m89/m91-verified):
//   A: lane(16g+r) holds A[r][8g..8g+7];  B: lane(16g+c) holds B[8g..8g+7][c]
//   C/D: col = lane&15, row = 4*(lane>>4) + reg
// xs/hs tiles XOR-swizzled: 16B-granule ^= (row&7)  (G4).
__global__ __launch_bounds__(256, 4) void node_update_mfma(
        const unsigned short* __restrict__ mg, const short* __restrict__ l2wT,
        const float* __restrict__ l2b, const short* __restrict__ lwT,
        const float* __restrict__ lb, float* __restrict__ h,
        const short* __restrict__ l1Tn, unsigned short* __restrict__ hwn) {
    __shared__ short xs[16 * 128];          // 4 KB bf16, swizzled
    __shared__ short hs[16 * 128];          // 4 KB bf16, swizzled
    const int t   = threadIdx.x;
    const int w   = t >> 6;                 // wave 0..3
    const int l   = t & 63;
    const int lr  = l & 15;
    const int lg  = l >> 4;                 // k-group 0..3
    const int nb  = blockIdx.x << 4;        // 16 nodes per block
    const int ft0 = w * 2, ft1 = w * 2 + 1;

    // ======== issue-early: every global load this kernel needs ========
    bf16x8 ma = *(const bf16x8*)(mg + (size_t)(nb + lr) * NFT + lg * 8);
    bf16x8 aw0 = *(const bf16x8*)(l2wT + (ft0 * 16 + lr) * 32 + lg * 8);
    bf16x8 aw1 = *(const bf16x8*)(l2wT + (ft1 * 16 + lr) * 32 + lg * 8);
    bf16x8 bw0[4], bw1[4];
    #pragma unroll
    for (int ks = 0; ks < 4; ++ks) {
        bw0[ks] = *(const bf16x8*)(lwT + (ft0 * 16 + lr) * 128 + ks * 32 + lg * 8);
        bw1[ks] = *(const bf16x8*)(lwT + (ft1 * 16 + lr) * 128 + ks * 32 + lg * 8);
    }
    float hold0[4], hold1[4];
    #pragma unroll
    for (int i = 0; i < 4; ++i) {
        hold0[i] = h[(size_t)(nb + lg * 4 + i) * HIDN + ft0 * 16 + lr];
        hold1[i] = h[(size_t)(nb + lg * 4 + i) * HIDN + ft1 * 16 + lr];
    }
    float biasA0 = l2b[ft0 * 16 + lr], biasA1 = l2b[ft1 * 16 + lr];
    float biasB0 = lb[ft0 * 16 + lr],  biasB1 = lb[ft1 * 16 + lr];

    // ======== phase A: x = ssp(m @ l2w + l2b) ========
    f32x4 cA0 = {0.f, 0.f, 0.f, 0.f}, cA1 = {0.f, 0.f, 0.f, 0.f};
    cA0 = __builtin_amdgcn_mfma_f32_16x16x32_bf16(ma, aw0, cA0, 0, 0, 0);
    cA1 = __builtin_amdgcn_mfma_f32_16x16x32_bf16(ma, aw1, cA1, 0, 0, 0);
    #pragma unroll
    for (int i = 0; i < 4; ++i) {
        int row = lg * 4 + i;
        int col0 = ft0 * 16 + lr;
        int col1 = ft1 * 16 + lr;
        xs[row * 128 + ((col0 >> 3) ^ (row & 7)) * 8 + (col0 & 7)] = f2bf(ssp(cA0[i] + biasA0));
        xs[row * 128 + ((col1 >> 3) ^ (row & 7)) * 8 + (col1 & 7)] = f2bf(ssp(cA1[i] + biasA1));
    }
    // issue phase-C weights while waiting at the barrier
    bf16x8 cw[4];
    if (l1Tn != nullptr && w < 2) {
        #pragma unroll
        for (int ks = 0; ks < 4; ++ks)
            cw[ks] = *(const bf16x8*)(l1Tn + (w * 16 + lr) * 128 + ks * 32 + lg * 8);
    }
    __syncthreads();

    // ======== phase B: h += x @ lw + lb  (K = 128) ========
    bf16x8 xa[4];
    #pragma unroll
    for (int ks = 0; ks < 4; ++ks)
        xa[ks] = *(const bf16x8*)(xs + lr * 128 + ((ks * 4 + lg) ^ (lr & 7)) * 8);
    f32x4 cB0 = {0.f, 0.f, 0.f, 0.f}, cB1 = {0.f, 0.f, 0.f, 0.f};
    #pragma unroll
    for (int ks = 0; ks < 4; ++ks)
        cB0 = __builtin_amdgcn_mfma_f32_16x16x32_bf16(xa[ks], bw0[ks], cB0, 0, 0, 0);
    #pragma unroll
    for (int ks = 0; ks < 4; ++ks)
        cB1 = __builtin_amdgcn_mfma_f32_16x16x32_bf16(xa[ks], bw1[ks], cB1, 0, 0, 0);
    #pragma unroll
    for (int i = 0; i < 4; ++i) {
        int node = nb + lg * 4 + i;
        int row = lg * 4 + i;
        float hv0 = hold0[i] + cB0[i] + biasB0;
        float hv1 = hold1[i] + cB1[i] + biasB1;
        h[(size_t)node * HIDN + ft0 * 16 + lr] = hv0;
        h[(size_t)node * HIDN + ft1 * 16 + lr] = hv1;
        int col0 = ft0 * 16 + lr;
        int col1 = ft1 * 16 + lr;
        hs[row * 128 + ((col0 >> 3) ^ (row & 7)) * 8 + (col0 & 7)] = f2bf(hv0);
        hs[row * 128 + ((col1 >> 3) ^ (row & 7)) * 8 + (col1 & 7)] = f2bf(hv1);
    }

    // ======== phase C: fused next-layer hw = h_new @ l1[l+1] (bf16 out) ====
    if (l1Tn != nullptr) {
        __syncthreads();
        if (w < 2) {
            bf16x8 ha[4];
            #pragma unroll
            for (int ks = 0; ks < 4; ++ks)
                ha[ks] = *(const bf16x8*)(hs + lr * 128 + ((ks * 4 + lg) ^ (lr & 7)) * 8);
            f32x4 c = {0.f, 0.f, 0.f, 0.f};
            #pragma unroll
            for (int ks = 0; ks < 4; ++ks)
                c = __builtin_amdgcn_mfma_f32_16x16x32_bf16(ha[ks], cw[ks], c, 0, 0, 0);
            #pragma unroll
            for (int i = 0; i < 4; ++i) {
                int node = nb + lg * 4 + i;
                hwn[(size_t)node * NFT + w * 16 + lr] = (unsigned short)f2bf(c[i]);
            }
        }
    }
}

// ---------------------------------------------------------------------------
extern "C" void kernel_launch(void* const* d_in, const int* in_sizes, int n_in,
                              void* d_out, int out_size, void* d_ws, size_t ws_size,
                              hipStream_t stream) {
    const int*   z    = (const int*)d_in[0];
    const float* pos  = (const float*)d_in[1];
    const int*   ei   = (const int*)d_in[2];    // [2][E]
    const float* mask = (const float*)d_in[3];
    const float* emb  = (const float*)d_in[4];
    const float* w1   = (const float*)d_in[5];  // [6][50][32]
    const float* b1   = (const float*)d_in[6];  // [6][32]
    const float* w2   = (const float*)d_in[7];  // [6][32][32]
    const float* b2   = (const float*)d_in[8];  // [6][32]
    const float* l1w  = (const float*)d_in[9];  // [6][128][32]
    const float* l2w  = (const float*)d_in[10]; // [6][32][128]
    const float* l2b  = (const float*)d_in[11]; // [6][128]
    const float* lww  = (const float*)d_in[12]; // [6][128][128]
    const float* lbb  = (const float*)d_in[13]; // [6][128]
    float* h = (float*)d_out;

    char* base = (char*)d_ws;
    size_t o = 0;
    auto alloc = [&](size_t bytes) -> void* {
        void* p = base + o;
        o += (bytes + 255) & ~(size_t)255;
        return p;
    };
    int*            d_rp    = (int*)alloc((NN + 1) * sizeof(int));
    float2*         d_geo   = (float2*)alloc((size_t)EE * sizeof(float2));
    unsigned short* d_tab2b = (unsigned short*)alloc((size_t)NLAY * TABN * NFT * 2 * sizeof(unsigned short));
    unsigned short* d_hwA   = (unsigned short*)alloc((size_t)NN * NFT * sizeof(unsigned short));
    unsigned short* d_hwB   = (unsigned short*)alloc((size_t)NN * NFT * sizeof(unsigned short));
    unsigned short* d_m     = (unsigned short*)alloc((size_t)NN * NFT * sizeof(unsigned short));
    short*          d_l2wT  = (short*)alloc((size_t)NLAY * 4096 * sizeof(short));
    short*          d_lwT   = (short*)alloc((size_t)NLAY * 16384 * sizeof(short));
    short*          d_l1T   = (short*)alloc((size_t)NLAY * 4096 * sizeof(short));
    (void)ws_size; (void)in_sizes; (void)n_in; (void)out_size;

    setup_kernel<<<NB_TAB + NB_GEO + NB_RP + NB_PREP, 256, 0, stream>>>(
        w1, b1, w2, b2, d_tab2b, ei, pos, mask, d_geo, d_rp,
        l2w, lww, l1w, d_l2wT, d_lwT, d_l1T);
    init_h_hw<<<NN / 8, 256, 0, stream>>>(z, (const float4*)emb, l1w,
                                          (float4*)h, d_hwA);

    for (int l = 0; l < NLAY; ++l) {
        const unsigned short* hwin  = (l & 1) ? d_hwB : d_hwA;
        unsigned short*       hwout = (l & 1) ? d_hwA : d_hwB;
        const short* l1Tn = (l + 1 < NLAY) ? (d_l1T + (size_t)(l + 1) * 4096) : nullptr;
        edge_agg<<<NN / 4, 256, 0, stream>>>(
            d_rp, ei, d_geo, (const unsigned*)(d_tab2b + (size_t)l * TABN * NFT * 2),
            hwin, d_m);
        node_update_mfma<<<NN / 16, 256, 0, stream>>>(
            d_m, d_l2wT + (size_t)l * 4096, l2b + (size_t)l * HIDN,
            d_lwT + (size_t)l * 16384, lbb + (size_t)l * HIDN, h, l1Tn, hwout);
    }
}

// Round 10
// 197.800 us; speedup vs baseline: 1.8618x; 1.0374x over previous
//
#include <hip/hip_runtime.h>
#include <math.h>

#define NN     16384
#define EE     600000
#define HIDN   128
#define NFT    32
#define NGAUSS 50
#define NLAY   6
#define TABN   8192
#define CUTF   10.0f

typedef float f32x4  __attribute__((ext_vector_type(4)));
typedef short bf16x8 __attribute__((ext_vector_type(8)));

__device__ __forceinline__ float ssp(float x) {
    // softplus(x) - log(2), numerically stable
    return fmaxf(x, 0.0f) + log1pf(__expf(-fabsf(x))) - 0.69314718055994531f;
}

__device__ __forceinline__ short f2bf(float x) {
    // f32 -> bf16 round-to-nearest-even
    union { float f; unsigned u; } v; v.f = x;
    unsigned r = v.u + 0x7fffu + ((v.u >> 16) & 1u);
    return (short)(r >> 16);
}

__device__ __forceinline__ float bf2f(unsigned u16) {
    union { unsigned u; float f; } v; v.u = u16 << 16;
    return v.f;
}

// ===================== merged setup kernel (block-range dispatch) ==========
// blocks [0, NB_TAB)               : tab build (packed bf16 pairs)
// blocks [NB_TAB, +NB_GEO)         : edge geom -> (u, v, i0*NFT) precompute
// blocks [.., +NB_RP)              : row_ptr binary search
// blocks [.., +NB_PREP)            : weight transpose+bf16
#define NB_TAB  (NLAY * TABN / 8)                   // 6144
#define NB_GEO  ((EE + 255) / 256)                  // 2344
#define NB_RP   ((NN + 1 + 255) / 256)              // 65
#define NB_PREP ((NLAY * 24576 + 255) / 256)        // 576

__global__ void setup_kernel(
        const float* __restrict__ w1, const float* __restrict__ b1,
        const float* __restrict__ w2, const float* __restrict__ b2,
        unsigned short* __restrict__ tab2b,
        const int* __restrict__ ei, const float* __restrict__ pos,
        const float* __restrict__ mask, float4* __restrict__ geo4,
        int* __restrict__ rp,
        const float* __restrict__ l2w, const float* __restrict__ lww,
        const float* __restrict__ l1w,
        short* __restrict__ l2wT, short* __restrict__ lwT,
        short* __restrict__ l1T) {
    __shared__ float ea[8][NGAUSS];
    __shared__ float t1[8][NFT];
    const int b = blockIdx.x;
    const int t = threadIdx.x;

    if (b < NB_TAB) {
        // ------- tab: tab2b[l][ent][f] = (bf16 W[ent][f], bf16 W[ent+1][f])
        int f = t & 31, g = t >> 5;
        int id = b * 8 + g;                 // 0 .. NLAY*TABN-1 exact
        int l = id / TABN, ent = id % TABN;
        float d = ent * (CUTF / (TABN - 1));
        const float delta = CUTF / (NGAUSS - 1);
        const float coeff = -0.5f / (delta * delta);
        for (int gg = f; gg < NGAUSS; gg += 32) {
            float diff = d - gg * delta;
            ea[g][gg] = __expf(coeff * diff * diff);
        }
        __syncthreads();
        float a = b1[l * NFT + f];
        const float* w1l = w1 + l * NGAUSS * NFT;
        #pragma unroll
        for (int gg = 0; gg < NGAUSS; ++gg)
            a = fmaf(ea[g][gg], w1l[gg * NFT + f], a);
        t1[g][f] = ssp(a);
        __syncthreads();
        float c = b2[l * NFT + f];
        const float* w2l = w2 + l * NFT * NFT;
        #pragma unroll
        for (int k = 0; k < NFT; ++k)
            c = fmaf(t1[g][k], w2l[k * NFT + f], c);
        unsigned short cb = (unsigned short)f2bf(c);
        size_t idx = (size_t)id * NFT + f;
        tab2b[2 * idx] = cb;                                  // .x of ent
        if (ent > 0)         tab2b[2 * (idx - NFT) + 1] = cb; // .y of ent-1
        if (ent == TABN - 1) tab2b[2 * idx + 1] = cb;         // clamp top
    } else if (b < NB_TAB + NB_GEO) {
        // ------- edge geom + lerp precompute:
        //   geo4[e] = (cc*(1-fr), cc*fr, bits(i0*NFT), 0)
        int e = (b - NB_TAB) * 256 + t;
        if (e >= EE) return;
        int s = ei[e], d2 = ei[EE + e];
        float dx = pos[s * 3 + 0] - pos[d2 * 3 + 0];
        float dy = pos[s * 3 + 1] - pos[d2 * 3 + 1];
        float dz = pos[s * 3 + 2] - pos[d2 * 3 + 2];
        float d = sqrtf(dx * dx + dy * dy + dz * dz);
        float cc = 0.5f * (cosf(d * 0.31415926535897932f) + 1.0f) * mask[e];
        float p = d * ((TABN - 1) / CUTF);
        int i0 = (int)p;
        i0 = (i0 > TABN - 2) ? (TABN - 2) : (i0 < 0 ? 0 : i0);
        float fr = p - (float)i0;
        float4 g;
        g.x = cc * (1.0f - fr);
        g.y = cc * fr;
        g.z = __int_as_float(i0 * NFT);
        g.w = 0.0f;
        geo4[e] = g;
    } else if (b < NB_TAB + NB_GEO + NB_RP) {
        // ------- row_ptr: key(e) = real ? dst[e] : INT_MAX, lower_bound
        int n = (b - NB_TAB - NB_GEO) * 256 + t;
        if (n > NN) return;
        const int* dst = ei + EE;
        int lo = 0, hi = EE;
        while (lo < hi) {
            int mid = (lo + hi) >> 1;
            int key = (mask[mid] > 0.5f) ? dst[mid] : 0x7fffffff;
            if (key < n) lo = mid + 1; else hi = mid;
        }
        rp[n] = lo;
    } else {
        // ------- weight transpose + bf16
        const int per = 4096 + 16384 + 4096;   // 24576 per layer
        int id = (b - NB_TAB - NB_GEO - NB_RP) * 256 + t;
        if (id >= NLAY * per) return;
        int l = id / per, r = id % per;
        if (r < 4096) {
            int f = r >> 5, k = r & 31;
            l2wT[l * 4096 + f * 32 + k] = f2bf(l2w[l * 4096 + k * 128 + f]);
        } else if (r < 4096 + 16384) {
            int q = r - 4096; int f = q >> 7, k = q & 127;
            lwT[l * 16384 + f * 128 + k] = f2bf(lww[l * 16384 + k * 128 + f]);
        } else {
            int q = r - 20480; int f = q >> 7, k = q & 127;   // f<32, k<128
            l1T[l * 4096 + f * 128 + k] = f2bf(l1w[l * 4096 + k * 32 + f]);
        }
    }
}

// ================= init h = emb[z] AND hw = h @ l1[0] (fused) ==============
// 8 nodes / 256-thr block. l1[0] staged f32 in LDS; h rows staged in LDS.
__global__ void init_h_hw(const int* __restrict__ z, const float4* __restrict__ emb4,
                          const float* __restrict__ l1w,
                          float4* __restrict__ h4, unsigned short* __restrict__ hw) {
    __shared__ float l1s[HIDN * NFT];       // 16 KB
    __shared__ float hls[8][HIDN];          // 4 KB
    int t = threadIdx.x, c = t & 31, nl = t >> 5;
    for (int i = t; i < HIDN * NFT / 4; i += 256)
        ((float4*)l1s)[i] = ((const float4*)l1w)[i];
    int node = blockIdx.x * 8 + nl;
    float4 hv = emb4[(size_t)z[node] * 32 + c];
    h4[(size_t)node * 32 + c] = hv;
    *(float4*)(&hls[nl][c * 4]) = hv;
    __syncthreads();
    // hw[node][f] = sum_k h[node][k] * l1[k][f]   (thread = (nl, f))
    float acc = 0.0f;
    #pragma unroll 16
    for (int k = 0; k < HIDN; ++k)
        acc = fmaf(hls[nl][k], l1s[k * NFT + c], acc);
    hw[(size_t)node * NFT + c] = (unsigned short)f2bf(acc);
}

// -------------------------------------------------- edge aggregate (CSR) ----
// One 64-lane wave per dst node: lane = (par, f); parity split + 8 unrolled
// independent bodies (e .. e+14 step 16) = 8 concurrent load chains per
// lane, 4 named accumulators. Per-edge lerp precomputed (u, v, i0*NFT):
// body = {src load, geo4 load} -> {tab u32 load, hw bf16 load} -> 3 fma.
#define EDGE_BODY(EIDX, ACC)                                               \
    {                                                                      \
        int e_ = (EIDX);                                                   \
        int s_ = src[e_];                                                  \
        float4 g_ = geo4[e_];                                              \
        int i0p_ = __float_as_int(g_.z);                                   \
        unsigned tv_ = tabL[i0p_ + f];                                     \
        float w0_ = bf2f(tv_ & 0xffffu);                                   \
        float w1_ = bf2f(tv_ >> 16);                                       \
        float t_ = g_.x * w0_ + g_.y * w1_;                                \
        float hv_ = bf2f(hw[(size_t)s_ * NFT + f]);                        \
        ACC = fmaf(hv_, t_, ACC);                                          \
    }

__global__ void edge_agg(const int* __restrict__ rp, const int* __restrict__ src,
                         const float4* __restrict__ geo4, const unsigned* __restrict__ tabL,
                         const unsigned short* __restrict__ hw,
                         unsigned short* __restrict__ m) {
    int t = threadIdx.x;
    int f = t & 31, par = (t >> 5) & 1, g = t >> 6;   // 4 nodes / 256-thr block
    int n = blockIdx.x * 4 + g;
    int r0 = rp[n], r1 = rp[n + 1];
    float acc0 = 0.0f, acc1 = 0.0f, acc2 = 0.0f, acc3 = 0.0f;
    int e = r0 + par;
    for (; e + 14 < r1; e += 16) {        // 8 independent chains
        EDGE_BODY(e,      acc0);
        EDGE_BODY(e + 2,  acc1);
        EDGE_BODY(e + 4,  acc2);
        EDGE_BODY(e + 6,  acc3);
        EDGE_BODY(e + 8,  acc0);
        EDGE_BODY(e + 10, acc1);
        EDGE_BODY(e + 12, acc2);
        EDGE_BODY(e + 14, acc3);
    }
    for (; e + 6 < r1; e += 8) {          // 4 chains
        EDGE_BODY(e,     acc0);
        EDGE_BODY(e + 2, acc1);
        EDGE_BODY(e + 4, acc2);
        EDGE_BODY(e + 6, acc3);
    }
    for (; e + 2 < r1; e += 4) {
        EDGE_BODY(e,     acc0);
        EDGE_BODY(e + 2, acc1);
    }
    if (e < r1) EDGE_BODY(e, acc0);
    float acc = (acc0 + acc1) + (acc2 + acc3);
    acc += __shfl_xor(acc, 32);
    if (par == 0) m[(size_t)n * NFT + f] = (unsigned short)f2bf(acc);
}

// --------------------------------- node update, MFMA (+ fused next-layer hw)
// x = ssp(m@l2w + l2b); h += x@lw + lb; hw_next = h_new @ l1[l+1]
// 512 threads = 8 waves; block owns 16 nodes; wave w owns f-tile w (ONE tile
// per wave -> half the per-wave serial work of r9, VGPR ~90 -> ~20 waves/CU).
// Grid NN/16 = 1024 blocks. ISSUE-EARLY operands.
// mfma_f32_16x16x32_bf16 layouts (m89/m91-verified):
//   A: lane(16g+r) holds A[r][8g..8g+7];  B: lane(16g+c) holds B[8g..8g+7][c]
//   C/D: col = lane&15, row = 4*(lane>>4) + reg
// xs/hs tiles XOR-swizzled: 16B-granule ^= (row&7)  (G4).
__global__ __launch_bounds__(512, 4) void node_update_mfma(
        const unsigned short* __restrict__ mg, const short* __restrict__ l2wT,
        const float* __restrict__ l2b, const short* __restrict__ lwT,
        const float* __restrict__ lb, float* __restrict__ h,
        const short* __restrict__ l1Tn, unsigned short* __restrict__ hwn) {
    __shared__ short xs[16 * 128];          // 4 KB bf16, swizzled
    __shared__ short hs[16 * 128];          // 4 KB bf16, swizzled
    const int t   = threadIdx.x;
    const int w   = t >> 6;                 // wave 0..7 = f-tile
    const int l   = t & 63;
    const int lr  = l & 15;
    const int lg  = l >> 4;                 // k-group 0..3
    const int nb  = blockIdx.x << 4;        // 16 nodes per block
    const int ft  = w;

    // ======== issue-early: every global load this kernel needs ========
    bf16x8 ma = *(const bf16x8*)(mg + (size_t)(nb + lr) * NFT + lg * 8);
    bf16x8 aw = *(const bf16x8*)(l2wT + (ft * 16 + lr) * 32 + lg * 8);
    bf16x8 bw[4];
    #pragma unroll
    for (int ks = 0; ks < 4; ++ks)
        bw[ks] = *(const bf16x8*)(lwT + (ft * 16 + lr) * 128 + ks * 32 + lg * 8);
    float hold[4];
    #pragma unroll
    for (int i = 0; i < 4; ++i)
        hold[i] = h[(size_t)(nb + lg * 4 + i) * HIDN + ft * 16 + lr];
    float biasA = l2b[ft * 16 + lr];
    float biasB = lb[ft * 16 + lr];

    // ======== phase A: x = ssp(m @ l2w + l2b) ========
    f32x4 cA = {0.f, 0.f, 0.f, 0.f};
    cA = __builtin_amdgcn_mfma_f32_16x16x32_bf16(ma, aw, cA, 0, 0, 0);
    #pragma unroll
    for (int i = 0; i < 4; ++i) {
        int row = lg * 4 + i;
        int col = ft * 16 + lr;
        xs[row * 128 + ((col >> 3) ^ (row & 7)) * 8 + (col & 7)] = f2bf(ssp(cA[i] + biasA));
    }
    // issue phase-C weights while waiting at the barrier
    bf16x8 cw[4];
    if (l1Tn != nullptr && w < 2) {
        #pragma unroll
        for (int ks = 0; ks < 4; ++ks)
            cw[ks] = *(const bf16x8*)(l1Tn + (w * 16 + lr) * 128 + ks * 32 + lg * 8);
    }
    __syncthreads();

    // ======== phase B: h += x @ lw + lb  (K = 128) ========
    bf16x8 xa[4];
    #pragma unroll
    for (int ks = 0; ks < 4; ++ks)
        xa[ks] = *(const bf16x8*)(xs + lr * 128 + ((ks * 4 + lg) ^ (lr & 7)) * 8);
    f32x4 cB = {0.f, 0.f, 0.f, 0.f};
    #pragma unroll
    for (int ks = 0; ks < 4; ++ks)
        cB = __builtin_amdgcn_mfma_f32_16x16x32_bf16(xa[ks], bw[ks], cB, 0, 0, 0);
    #pragma unroll
    for (int i = 0; i < 4; ++i) {
        int node = nb + lg * 4 + i;
        int row = lg * 4 + i;
        float hv = hold[i] + cB[i] + biasB;
        h[(size_t)node * HIDN + ft * 16 + lr] = hv;
        int col = ft * 16 + lr;
        hs[row * 128 + ((col >> 3) ^ (row & 7)) * 8 + (col & 7)] = f2bf(hv);
    }

    // ======== phase C: fused next-layer hw = h_new @ l1[l+1] (bf16 out) ====
    if (l1Tn != nullptr) {
        __syncthreads();
        if (w < 2) {
            bf16x8 ha[4];
            #pragma unroll
            for (int ks = 0; ks < 4; ++ks)
                ha[ks] = *(const bf16x8*)(hs + lr * 128 + ((ks * 4 + lg) ^ (lr & 7)) * 8);
            f32x4 c = {0.f, 0.f, 0.f, 0.f};
            #pragma unroll
            for (int ks = 0; ks < 4; ++ks)
                c = __builtin_amdgcn_mfma_f32_16x16x32_bf16(ha[ks], cw[ks], c, 0, 0, 0);
            #pragma unroll
            for (int i = 0; i < 4; ++i) {
                int node = nb + lg * 4 + i;
                hwn[(size_t)node * NFT + w * 16 + lr] = (unsigned short)f2bf(c[i]);
            }
        }
    }
}

// ---------------------------------------------------------------------------
extern "C" void kernel_launch(void* const* d_in, const int* in_sizes, int n_in,
                              void* d_out, int out_size, void* d_ws, size_t ws_size,
                              hipStream_t stream) {
    const int*   z    = (const int*)d_in[0];
    const float* pos  = (const float*)d_in[1];
    const int*   ei   = (const int*)d_in[2];    // [2][E]
    const float* mask = (const float*)d_in[3];
    const float* emb  = (const float*)d_in[4];
    const float* w1   = (const float*)d_in[5];  // [6][50][32]
    const float* b1   = (const float*)d_in[6];  // [6][32]
    const float* w2   = (const float*)d_in[7];  // [6][32][32]
    const float* b2   = (const float*)d_in[8];  // [6][32]
    const float* l1w  = (const float*)d_in[9];  // [6][128][32]
    const float* l2w  = (const float*)d_in[10]; // [6][32][128]
    const float* l2b  = (const float*)d_in[11]; // [6][128]
    const float* lww  = (const float*)d_in[12]; // [6][128][128]
    const float* lbb  = (const float*)d_in[13]; // [6][128]
    float* h = (float*)d_out;

    char* base = (char*)d_ws;
    size_t o = 0;
    auto alloc = [&](size_t bytes) -> void* {
        void* p = base + o;
        o += (bytes + 255) & ~(size_t)255;
        return p;
    };
    int*            d_rp    = (int*)alloc((NN + 1) * sizeof(int));
    float4*         d_geo4  = (float4*)alloc((size_t)EE * sizeof(float4));
    unsigned short* d_tab2b = (unsigned short*)alloc((size_t)NLAY * TABN * NFT * 2 * sizeof(unsigned short));
    unsigned short* d_hwA   = (unsigned short*)alloc((size_t)NN * NFT * sizeof(unsigned short));
    unsigned short* d_hwB   = (unsigned short*)alloc((size_t)NN * NFT * sizeof(unsigned short));
    unsigned short* d_m     = (unsigned short*)alloc((size_t)NN * NFT * sizeof(unsigned short));
    short*          d_l2wT  = (short*)alloc((size_t)NLAY * 4096 * sizeof(short));
    short*          d_lwT   = (short*)alloc((size_t)NLAY * 16384 * sizeof(short));
    short*          d_l1T   = (short*)alloc((size_t)NLAY * 4096 * sizeof(short));
    (void)ws_size; (void)in_sizes; (void)n_in; (void)out_size;

    setup_kernel<<<NB_TAB + NB_GEO + NB_RP + NB_PREP, 256, 0, stream>>>(
        w1, b1, w2, b2, d_tab2b, ei, pos, mask, d_geo4, d_rp,
        l2w, lww, l1w, d_l2wT, d_lwT, d_l1T);
    init_h_hw<<<NN / 8, 256, 0, stream>>>(z, (const float4*)emb, l1w,
                                          (float4*)h, d_hwA);

    for (int l = 0; l < NLAY; ++l) {
        const unsigned short* hwin  = (l & 1) ? d_hwB : d_hwA;
        unsigned short*       hwout = (l & 1) ? d_hwA : d_hwB;
        const short* l1Tn = (l + 1 < NLAY) ? (d_l1T + (size_t)(l + 1) * 4096) : nullptr;
        edge_agg<<<NN / 4, 256, 0, stream>>>(
            d_rp, ei, d_geo4, (const unsigned*)(d_tab2b + (size_t)l * TABN * NFT * 2),
            hwin, d_m);
        node_update_mfma<<<NN / 16, 512, 0, stream>>>(
            d_m, d_l2wT + (size_t)l * 4096, l2b + (size_t)l * HIDN,
            d_lwT + (size_t)l * 16384, lbb + (size_t)l * HIDN, h, l1Tn, hwout);
    }
}